// Round 14
// baseline (411.215 us; speedup 1.0000x reference)
//
#include <hip/hip_runtime.h>
#include <math.h>

#define NN 768
#define CS 384
#define CZ 128
#define CH 16
#define HH 12
#define PQ 4
#define PV 8
#define OUTIN 2112

#define SC_QK 0.14433756729740643f   // sqrt(1/(3*16))
#define SC_B  0.57735026918962576f   // sqrt(1/3)
#define SC_HW 0.13608276348795434f   // sqrt(2/(27*4))
#define MSLACK 12.0f                 // safe-softmax headroom over lqd row max

// DPP cross-lane ops on the VALU pipe (no LDS/swizzle issue).
// After xor1+xor2, quad-mates are equal, so half_mirror(0x141) acts as xor4
// and row_mirror(0x140) as xor8 -> full 16-lane butterfly on DPP.
__device__ __forceinline__ float dpp_add(float x, const int ctrl) {
    int yi;
    switch (ctrl) {
        case 0: yi = __builtin_amdgcn_update_dpp(0, __float_as_int(x), 0xB1,  0xf, 0xf, true); break;
        case 1: yi = __builtin_amdgcn_update_dpp(0, __float_as_int(x), 0x4E,  0xf, 0xf, true); break;
        case 2: yi = __builtin_amdgcn_update_dpp(0, __float_as_int(x), 0x141, 0xf, 0xf, true); break;
        default:yi = __builtin_amdgcn_update_dpp(0, __float_as_int(x), 0x140, 0xf, 0xf, true); break;
    }
    return x + __int_as_float(yi);
}
__device__ __forceinline__ float dpp_max(float x, const int ctrl) {
    int yi;
    switch (ctrl) {
        case 0: yi = __builtin_amdgcn_update_dpp(0, __float_as_int(x), 0xB1,  0xf, 0xf, true); break;
        case 1: yi = __builtin_amdgcn_update_dpp(0, __float_as_int(x), 0x4E,  0xf, 0xf, true); break;
        case 2: yi = __builtin_amdgcn_update_dpp(0, __float_as_int(x), 0x141, 0xf, 0xf, true); break;
        default:yi = __builtin_amdgcn_update_dpp(0, __float_as_int(x), 0x140, 0xf, 0xf, true); break;
    }
    return fmaxf(x, __int_as_float(yi));
}

// ---------------- Kernel A: input projections (s @ W.T + b) ----------------
__global__ __launch_bounds__(256) void kproj(
    const float* __restrict__ s,
    const float* __restrict__ Wq,  const float* __restrict__ bq,
    const float* __restrict__ Wkv, const float* __restrict__ bkv,
    const float* __restrict__ Wqp, const float* __restrict__ bqp,
    const float* __restrict__ Wkvp,const float* __restrict__ bkvp,
    float* __restrict__ q, float* __restrict__ kT, float* __restrict__ vall,
    float* __restrict__ qpr, float* __restrict__ kvpr)
{
    __shared__ float s_lds[8*384];
    int n0 = blockIdx.x * 8;
    int t = threadIdx.x;
    for (int idx = t; idx < 8*384; idx += 256)
        s_lds[idx] = s[(n0 + idx/384)*384 + (idx%384)];
    __syncthreads();

    int o = blockIdx.y * 128 + (t & 127);
    int ng = t >> 7;
    const float* wrow; float bias;
    if (o < 192)      { wrow = Wq   + o*384;       bias = bq[o]; }
    else if (o < 576) { wrow = Wkv  + (o-192)*384; bias = bkv[o-192]; }
    else if (o < 720) { wrow = Wqp  + (o-576)*384; bias = bqp[o-576]; }
    else              { wrow = Wkvp + (o-720)*384; bias = bkvp[o-720]; }

    float acc[4] = {bias, bias, bias, bias};
    const float4* wr4 = reinterpret_cast<const float4*>(wrow);
    for (int c4 = 0; c4 < 96; ++c4) {
        float4 w = wr4[c4];
        #pragma unroll
        for (int nn = 0; nn < 4; ++nn) {
            const float* sr = &s_lds[(ng*4+nn)*384 + c4*4];
            acc[nn] = fmaf(w.x, sr[0], acc[nn]);
            acc[nn] = fmaf(w.y, sr[1], acc[nn]);
            acc[nn] = fmaf(w.z, sr[2], acc[nn]);
            acc[nn] = fmaf(w.w, sr[3], acc[nn]);
        }
    }
    #pragma unroll
    for (int nn = 0; nn < 4; ++nn) {
        int n = n0 + ng*4 + nn;
        float v = acc[nn];
        if (o < 192)      q[n*192 + o] = v;
        else if (o < 576) {
            int oo = o - 192, h = oo >> 5, cc = oo & 31;
            if (cc < 16) kT[(h*NN + n)*16 + cc] = v;
            else         vall[(size_t)n*480 + h*40 + (cc-16)] = v;
        }
        else if (o < 720) qpr[n*144 + (o-576)] = v;
        else              kvpr[n*432 + (o-720)] = v;
    }
}

// ---------------- Kernel B: apply frames (rot, trans) to points ----------------
__global__ __launch_bounds__(192) void krot(
    const float* __restrict__ rot, const float* __restrict__ trans,
    const float* __restrict__ qpr, const float* __restrict__ kvpr,
    float* __restrict__ qp, float* __restrict__ kpT, float* __restrict__ vall)
{
    int n = blockIdx.x;
    __shared__ float R[9], T[3];
    int t = threadIdx.x;
    if (t < 9) R[t] = rot[n*9 + t];
    if (t < 3) T[t] = trans[n*3 + t];
    __syncthreads();

    const float* src = (t < 48) ? (qpr + n*144 + t*3) : (kvpr + n*432 + (t-48)*3);
    float x = src[0], y = src[1], z = src[2];
    float wx = R[0]*x + R[1]*y + R[2]*z + T[0];
    float wy = R[3]*x + R[4]*y + R[5]*z + T[1];
    float wz = R[6]*x + R[7]*y + R[8]*z + T[2];
    if (t < 48) {
        float* d = qp + n*144 + t*3;
        d[0]=wx; d[1]=wy; d[2]=wz;
    } else {
        int pi = t - 48, h = pi/12, pp = pi%12;
        if (pp < 4) {
            float* d = kpT + (h*NN+n)*12 + pp*3;
            d[0]=wx; d[1]=wy; d[2]=wz;
        } else {
            float* d = vall + (size_t)n*480 + h*40 + 16 + (pp-4)*3;
            d[0]=wx; d[1]=wy; d[2]=wz;
        }
    }
}

// ---------------- Kernel C1: z-independent logits + per-tile row max ----------------
__global__ __launch_bounds__(256) void kqk(
    const float* __restrict__ kT, const float* __restrict__ kpT,
    const float* __restrict__ q, const float* __restrict__ qp,
    const float* __restrict__ mask, const float* __restrict__ head_w,
    const float* __restrict__ bb, float* __restrict__ lqd,
    float* __restrict__ mpart)
{
    const int j0 = blockIdx.x * 64;
    const int i0 = blockIdx.y * 32;
    __shared__ float ktl[64][17], kpl[64][13];
    __shared__ float ql[32][17],  qpl[32][13];
    __shared__ float mi_l[32], mj_l[64];
    __shared__ float mpl[32][12];
    const int t = threadIdx.x;
    if (t < 32) mi_l[t] = mask[i0 + t];
    if (t < 64) mj_l[t] = mask[j0 + t];

    const int jl = t & 63, wv = t >> 6;

    for (int h = 0; h < 12; ++h) {
        __syncthreads();
        for (int idx = t; idx < 1024; idx += 256)
            ktl[idx >> 4][idx & 15] = kT[(size_t)(h*NN + j0 + (idx >> 4))*16 + (idx & 15)];
        for (int idx = t; idx < 768; idx += 256) {
            int r = idx / 12, e = idx - r*12;
            kpl[r][e] = kpT[(size_t)(h*NN + j0 + r)*12 + e];
        }
        for (int idx = t; idx < 512; idx += 256)
            ql[idx >> 4][idx & 15] = q[(i0 + (idx >> 4))*192 + h*16 + (idx & 15)];
        for (int idx = t; idx < 384; idx += 256) {
            int r = idx / 12, e = idx - r*12;
            qpl[r][e] = qp[(i0 + r)*144 + h*12 + e];
        }
        __syncthreads();

        const float hwh = log1pf(expf(head_w[h])) * SC_HW;
        const float bbh = bb[h] * SC_B;
        const float mj = mj_l[jl];
        #pragma unroll
        for (int k = 0; k < 8; ++k) {
            const int il = wv*8 + k;
            float qk = 0.f;
            #pragma unroll
            for (int c = 0; c < 16; ++c) qk = fmaf(ktl[jl][c], ql[il][c], qk);
            float d2 = 0.f;
            #pragma unroll
            for (int e = 0; e < 12; ++e) { float d = qpl[il][e] - kpl[jl][e]; d2 = fmaf(d, d, d2); }
            float mt = 1e9f * (mi_l[il]*mj - 1.0f);
            float lg = fmaf(qk, SC_QK, fmaf(-0.5f*hwh, d2, bbh)) + mt;
            lqd[((size_t)(i0+il)*NN + j0 + jl)*12 + h] = lg;
            float m = lg;
            m = dpp_max(m, 0);
            m = dpp_max(m, 1);
            m = dpp_max(m, 2);
            m = dpp_max(m, 3);
            m = fmaxf(m, __shfl_xor(m, 16, 64));
            m = fmaxf(m, __shfl_xor(m, 32, 64));
            if (jl == 0) mpl[il][h] = m;
        }
    }
    __syncthreads();
    if (t < 384) {
        int il = t / 12, h = t - il*12;
        mpart[((size_t)h*NN + i0 + il)*12 + blockIdx.x] = mpl[il][h];
    }
}

// ---------------- Kernel C2: FUSED bias + safe-M exp + o_pair/o/o_pt partials ----------------
// grid (768 i, 4 jsegs of 192). z read from HBM exactly once (phase-1); phase-2
// re-reads are L1/L2-hot. p in LDS in BOTH layouts: p_T[j][h] (float4-across-h
// for phase 2a) and p_lds[h][j] (float4-across-j for phase 2b).
__global__ __launch_bounds__(256) void kfuse(
    const float* __restrict__ z, const float* __restrict__ Wb,
    const float* __restrict__ lqd, const float* __restrict__ mpart,
    const float* __restrict__ vall,
    float* __restrict__ opart, float* __restrict__ vpart, float* __restrict__ ssum)
{
    __shared__ float  M_lds[12];
    __shared__ __align__(16) float p_lds[12][68];   // for phase 2b
    __shared__ __align__(16) float p_T[64][16];     // for phase 2a
    __shared__ float2 ofold[4][12][64];             // 24 KB
    __shared__ float  sredL[16][6];

    const int i = blockIdx.x, jseg = blockIdx.y;
    const int t = threadIdx.x, w = t >> 6, l = t & 63;
    const int gid = t >> 4, cl = t & 15;
    const int hhalf = gid & 1, h0 = hhalf * 6, jofs = gid >> 1;

    if (t < 12) {
        const float4* mp = (const float4*)(mpart + ((size_t)t*NN + i)*12);
        float4 a = mp[0], b = mp[1], c = mp[2];
        float m = fmaxf(fmaxf(fmaxf(a.x,a.y), fmaxf(a.z,a.w)),
                 fmaxf(fmaxf(fmaxf(b.x,b.y), fmaxf(b.z,b.w)),
                       fmaxf(fmaxf(c.x,c.y), fmaxf(c.z,c.w))));
        M_lds[t] = m + MSLACK;
    }

    // Wb fragment: heads h0..h0+5, channels cl*8..cl*8+7  (12 float4 = 48 VGPR)
    float4 wva[6], wvb[6];
    #pragma unroll
    for (int h = 0; h < 6; ++h) {
        const float4* wp = (const float4*)(Wb + (h0+h)*CZ + cl*8);
        wva[h] = wp[0]; wvb[h] = wp[1];
    }

    float2 oa[12];
    #pragma unroll
    for (int h = 0; h < 12; ++h) { oa[h].x = 0.f; oa[h].y = 0.f; }
    float2 vacc; vacc.x = 0.f; vacc.y = 0.f;
    const int vch = 2*t;            // valid for t<240
    const int vh  = (t < 240) ? (vch / 40) : 0;
    float s_acc = 0.f;

    __syncthreads();
    const float Mh = M_lds[h0 + (cl < 6 ? cl : 5)];
    const int jbase = jseg * 192;

    for (int tile = 0; tile < 3; ++tile) {
        const int jt = jbase + tile*64;

        // ---- phase 1: bias dot + p into LDS (reduce on DPP) ----
        {
            const float4* zq0 = (const float4*)(z + ((size_t)i*NN + jt + jofs)*CZ) + cl*2;
            float4 za = zq0[0], zb = zq0[1];
            for (int it = 0; it < 8; ++it) {
                float4 zaN = za, zbN = zb;
                if (it + 1 < 8) {
                    const float4* zq = (const float4*)(z + ((size_t)i*NN + jt + (it+1)*8 + jofs)*CZ) + cl*2;
                    zaN = zq[0]; zbN = zq[1];
                }
                const int j = jt + it*8 + jofs;
                float b0, b1, b2, b3, b4, b5;
                #define BDOT(BV, H)                                \
                    BV = za.x*wva[H].x;                            \
                    BV = fmaf(za.y, wva[H].y, BV);                 \
                    BV = fmaf(za.z, wva[H].z, BV);                 \
                    BV = fmaf(za.w, wva[H].w, BV);                 \
                    BV = fmaf(zb.x, wvb[H].x, BV);                 \
                    BV = fmaf(zb.y, wvb[H].y, BV);                 \
                    BV = fmaf(zb.z, wvb[H].z, BV);                 \
                    BV = fmaf(zb.w, wvb[H].w, BV);
                BDOT(b0, 0) BDOT(b1, 1) BDOT(b2, 2) BDOT(b3, 3) BDOT(b4, 4) BDOT(b5, 5)
                #undef BDOT
                #define BRED(BV)                                   \
                    BV = dpp_add(BV, 0);                           \
                    BV = dpp_add(BV, 1);                           \
                    BV = dpp_add(BV, 2);                           \
                    BV = dpp_add(BV, 3);
                BRED(b0) BRED(b1) BRED(b2) BRED(b3) BRED(b4) BRED(b5)
                #undef BRED
                float bsel = b0;
                bsel = (cl == 1) ? b1 : bsel;
                bsel = (cl == 2) ? b2 : bsel;
                bsel = (cl == 3) ? b3 : bsel;
                bsel = (cl == 4) ? b4 : bsel;
                bsel = (cl == 5) ? b5 : bsel;
                if (cl < 6) {
                    float g = fmaf(bsel, SC_B, lqd[((size_t)i*NN + j)*12 + h0 + cl]);
                    float p = __expf(g - Mh);
                    p_lds[h0 + cl][j - jt] = p;
                    p_T[j - jt][h0 + cl] = p;
                    s_acc += p;
                }
                za = zaN; zb = zbN;
            }
        }
        __syncthreads();   // p complete for this tile

        // ---- phase 2a: o_pair partial; p via 3 float4 broadcasts per j ----
        {
            const float2* zr2 = (const float2*)(z + (size_t)i*NN*CZ) + l;
            #pragma unroll 4
            for (int jj = 0; jj < 16; ++jj) {
                const int jb = jj*4 + w;
                float2 zv = zr2[(size_t)(jt + jb)*64];
                float4 pA = *(const float4*)&p_T[jb][0];
                float4 pB = *(const float4*)&p_T[jb][4];
                float4 pC = *(const float4*)&p_T[jb][8];
                oa[0].x  = fmaf(pA.x, zv.x, oa[0].x);  oa[0].y  = fmaf(pA.x, zv.y, oa[0].y);
                oa[1].x  = fmaf(pA.y, zv.x, oa[1].x);  oa[1].y  = fmaf(pA.y, zv.y, oa[1].y);
                oa[2].x  = fmaf(pA.z, zv.x, oa[2].x);  oa[2].y  = fmaf(pA.z, zv.y, oa[2].y);
                oa[3].x  = fmaf(pA.w, zv.x, oa[3].x);  oa[3].y  = fmaf(pA.w, zv.y, oa[3].y);
                oa[4].x  = fmaf(pB.x, zv.x, oa[4].x);  oa[4].y  = fmaf(pB.x, zv.y, oa[4].y);
                oa[5].x  = fmaf(pB.y, zv.x, oa[5].x);  oa[5].y  = fmaf(pB.y, zv.y, oa[5].y);
                oa[6].x  = fmaf(pB.z, zv.x, oa[6].x);  oa[6].y  = fmaf(pB.z, zv.y, oa[6].y);
                oa[7].x  = fmaf(pB.w, zv.x, oa[7].x);  oa[7].y  = fmaf(pB.w, zv.y, oa[7].y);
                oa[8].x  = fmaf(pC.x, zv.x, oa[8].x);  oa[8].y  = fmaf(pC.x, zv.y, oa[8].y);
                oa[9].x  = fmaf(pC.y, zv.x, oa[9].x);  oa[9].y  = fmaf(pC.y, zv.y, oa[9].y);
                oa[10].x = fmaf(pC.z, zv.x, oa[10].x); oa[10].y = fmaf(pC.z, zv.y, oa[10].y);
                oa[11].x = fmaf(pC.w, zv.x, oa[11].x); oa[11].y = fmaf(pC.w, zv.y, oa[11].y);
            }
        }

        // ---- phase 2b: o/o_pt partial; p via float4 LDS broadcast ----
        if (t < 240) {
            const float2* vr = (const float2*)(vall + (size_t)jt*480 + vch);
            #pragma unroll 4
            for (int q4 = 0; q4 < 16; ++q4) {
                float4 pv = *(const float4*)&p_lds[vh][q4*4];
                float2 v0 = vr[(size_t)(q4*4+0)*240];
                float2 v1 = vr[(size_t)(q4*4+1)*240];
                float2 v2 = vr[(size_t)(q4*4+2)*240];
                float2 v3 = vr[(size_t)(q4*4+3)*240];
                vacc.x = fmaf(pv.x, v0.x, vacc.x); vacc.y = fmaf(pv.x, v0.y, vacc.y);
                vacc.x = fmaf(pv.y, v1.x, vacc.x); vacc.y = fmaf(pv.y, v1.y, vacc.y);
                vacc.x = fmaf(pv.z, v2.x, vacc.x); vacc.y = fmaf(pv.z, v2.y, vacc.y);
                vacc.x = fmaf(pv.w, v3.x, vacc.x); vacc.y = fmaf(pv.w, v3.y, vacc.y);
            }
        }
        __syncthreads();   // p reads done -> next tile may overwrite
    }

    // ---- folds & partial writes ----
    #pragma unroll
    for (int h = 0; h < 12; ++h) ofold[w][h][l] = oa[h];
    if (cl < 6) sredL[gid][cl] = s_acc;
    if (t < 240)
        *((float2*)(vpart + ((size_t)(jseg*NN + i))*480) + t) = vacc;
    __syncthreads();

    float2* opw = (float2*)(opart + ((size_t)(jseg*NN + i))*1536);
    #pragma unroll
    for (int k = 0; k < 3; ++k) {
        int slot = k*256 + t;
        int h = slot >> 6, c2 = slot & 63;
        float2 v0 = ofold[0][h][c2], v1 = ofold[1][h][c2];
        float2 v2 = ofold[2][h][c2], v3 = ofold[3][h][c2];
        float2 o;
        o.x = v0.x + v1.x + v2.x + v3.x;
        o.y = v0.y + v1.y + v2.y + v3.y;
        opw[slot] = o;
    }
    if (t < 12) {
        float sv = 0.f;
        #pragma unroll
        for (int k = 0; k < 8; ++k) sv += sredL[k*2 + (t/6)][t % 6];
        ssum[(size_t)(jseg*12 + t)*NN + i] = sv;
    }
}

// ---------------- Kernel C3: combine 4 partials, normalize, epilogue ----------------
__global__ __launch_bounds__(256) void kepi(
    const float* __restrict__ opart, const float* __restrict__ vpart,
    const float* __restrict__ ssum, const float* __restrict__ rot,
    const float* __restrict__ trans, float* __restrict__ cat)
{
    __shared__ float sinv[12];
    __shared__ float optl[12][24];
    __shared__ float R[9], T[3];
    const int i = blockIdx.x, t = threadIdx.x;
    if (t < 9) R[t] = rot[i*9 + t];
    if (t < 3) T[t] = trans[i*3 + t];
    if (t >= 16 && t < 28) {
        int h = t - 16;
        sinv[h] = 1.0f / (ssum[(size_t)h*NN + i] + ssum[(size_t)(12+h)*NN + i]
                        + ssum[(size_t)(24+h)*NN + i] + ssum[(size_t)(36+h)*NN + i]);
    }
    __syncthreads();

    float* crow = cat + (size_t)i*OUTIN;
    const float2* op0 = (const float2*)(opart + (size_t)i*1536);
    const float2* op1 = (const float2*)(opart + (size_t)(NN + i)*1536);
    const float2* op2 = (const float2*)(opart + (size_t)(2*NN + i)*1536);
    const float2* op3 = (const float2*)(opart + (size_t)(3*NN + i)*1536);
    #pragma unroll
    for (int k = 0; k < 3; ++k) {
        int slot = k*256 + t;
        int h = slot >> 6, c2 = slot & 63;
        float2 a = op0[slot], b = op1[slot], c = op2[slot], d = op3[slot];
        float sc = sinv[h];
        float2 o;
        o.x = (a.x + b.x + c.x + d.x)*sc;
        o.y = (a.y + b.y + c.y + d.y)*sc;
        *(float2*)(crow + 576 + h*128 + c2*2) = o;
    }
    if (t < 240) {
        const int ch = 2*t, h = ch/40, e = ch%40;
        float2 v0 = *(const float2*)(vpart + (size_t)i*480 + ch);
        float2 v1 = *(const float2*)(vpart + (size_t)(NN + i)*480 + ch);
        float2 v2 = *(const float2*)(vpart + (size_t)(2*NN + i)*480 + ch);
        float2 v3 = *(const float2*)(vpart + (size_t)(3*NN + i)*480 + ch);
        float sc = sinv[h];
        float vx = (v0.x + v1.x + v2.x + v3.x)*sc;
        float vy = (v0.y + v1.y + v2.y + v3.y)*sc;
        if (e < 16) { crow[h*16 + e] = vx; crow[h*16 + e + 1] = vy; }
        else        { optl[h][e-16] = vx; optl[h][e-15] = vy; }
    }
    __syncthreads();
    if (t < 96) {
        int h = t >> 3, pp = t & 7;
        float wx = optl[h][pp*3+0] - T[0];
        float wy = optl[h][pp*3+1] - T[1];
        float wz = optl[h][pp*3+2] - T[2];
        crow[192 + 0*96 + h*8 + pp] = R[0]*wx + R[3]*wy + R[6]*wz;
        crow[192 + 1*96 + h*8 + pp] = R[1]*wx + R[4]*wy + R[7]*wz;
        crow[192 + 2*96 + h*8 + pp] = R[2]*wx + R[5]*wy + R[8]*wz;
        crow[480 + h*8 + pp] = sqrtf(fmaf(wx,wx,fmaf(wy,wy,wz*wz)) + 1e-8f);
    }
}

// ---------------- Kernel D1: out partial = cat-tile @ Wout-tile^T (split-K) ----------------
__global__ __launch_bounds__(256) void koutp(
    const float* __restrict__ cat, const float* __restrict__ Wout,
    float* __restrict__ ptmp)
{
    __shared__ float ct[32][36];
    __shared__ float wt[64][36];
    const int n0 = blockIdx.x * 32, o0 = blockIdx.y * 64;
    const int k0 = blockIdx.z * 352;
    const int t = threadIdx.x;
    const int tn = (t >> 4) * 2;
    const int to = t & 15;

    float a00=0,a01=0,a02=0,a03=0, a10=0,a11=0,a12=0,a13=0;

    for (int c = 0; c < 11; ++c) {
        __syncthreads();
        #pragma unroll
        for (int u = 0; u < 4; ++u) {
            int idx = u*256 + t, r = idx >> 5, cc = idx & 31;
            ct[r][cc] = cat[(size_t)(n0 + r)*OUTIN + k0 + c*32 + cc];
        }
        #pragma unroll
        for (int u = 0; u < 8; ++u) {
            int idx = u*256 + t, r = idx >> 5, cc = idx & 31;
            wt[r][cc] = Wout[(size_t)(o0 + r)*OUTIN + k0 + c*32 + cc];
        }
        __syncthreads();
        #pragma unroll
        for (int kk = 0; kk < 32; kk += 4) {
            float4 c0 = *(const float4*)&ct[tn][kk];
            float4 c1 = *(const float4*)&ct[tn+1][kk];
            float4 w0 = *(const float4*)&wt[to][kk];
            float4 w1 = *(const float4*)&wt[to+16][kk];
            float4 w2 = *(const float4*)&wt[to+32][kk];
            float4 w3 = *(const float4*)&wt[to+48][kk];
            a00 = fmaf(c0.x,w0.x,a00); a00 = fmaf(c0.y,w0.y,a00); a00 = fmaf(c0.z,w0.z,a00); a00 = fmaf(c0.w,w0.w,a00);
            a01 = fmaf(c0.x,w1.x,a01); a01 = fmaf(c0.y,w1.y,a01); a01 = fmaf(c0.z,w1.z,a01); a01 = fmaf(c0.w,w1.w,a01);
            a02 = fmaf(c0.x,w2.x,a02); a02 = fmaf(c0.y,w2.y,a02); a02 = fmaf(c0.z,w2.z,a02); a02 = fmaf(c0.w,w2.w,a02);
            a03 = fmaf(c0.x,w3.x,a03); a03 = fmaf(c0.y,w3.y,a03); a03 = fmaf(c0.z,w3.z,a03); a03 = fmaf(c0.w,w3.w,a03);
            a10 = fmaf(c1.x,w0.x,a10); a10 = fmaf(c1.y,w0.y,a10); a10 = fmaf(c1.z,w0.z,a10); a10 = fmaf(c1.w,w0.w,a10);
            a11 = fmaf(c1.x,w1.x,a11); a11 = fmaf(c1.y,w1.y,a11); a11 = fmaf(c1.z,w1.z,a11); a11 = fmaf(c1.w,w1.w,a11);
            a12 = fmaf(c1.x,w2.x,a12); a12 = fmaf(c1.y,w2.y,a12); a12 = fmaf(c1.z,w2.z,a12); a12 = fmaf(c1.w,w2.w,a12);
            a13 = fmaf(c1.x,w3.x,a13); a13 = fmaf(c1.y,w3.y,a13); a13 = fmaf(c1.z,w3.z,a13); a13 = fmaf(c1.w,w3.w,a13);
        }
    }
    float* pb = ptmp + (size_t)blockIdx.z * (NN*384);
    pb[(size_t)(n0+tn+0)*384 + o0+to+ 0] = a00;
    pb[(size_t)(n0+tn+0)*384 + o0+to+16] = a01;
    pb[(size_t)(n0+tn+0)*384 + o0+to+32] = a02;
    pb[(size_t)(n0+tn+0)*384 + o0+to+48] = a03;
    pb[(size_t)(n0+tn+1)*384 + o0+to+ 0] = a10;
    pb[(size_t)(n0+tn+1)*384 + o0+to+16] = a11;
    pb[(size_t)(n0+tn+1)*384 + o0+to+32] = a12;
    pb[(size_t)(n0+tn+1)*384 + o0+to+48] = a13;
}

// ---------------- Kernel D2: reduce split-K partials + bias ----------------
__global__ __launch_bounds__(256) void kred(
    const float* __restrict__ ptmp, const float* __restrict__ bout,
    float* __restrict__ out)
{
    int idx = blockIdx.x * 256 + threadIdx.x;
    int o = idx % 384;
    float v = bout[o];
    #pragma unroll
    for (int s = 0; s < 6; ++s) v += ptmp[(size_t)s*(NN*384) + idx];
    out[idx] = v;
}

extern "C" void kernel_launch(void* const* d_in, const int* in_sizes, int n_in,
                              void* d_out, int out_size, void* d_ws, size_t ws_size,
                              hipStream_t stream) {
    const float* s      = (const float*)d_in[0];
    const float* z      = (const float*)d_in[1];
    const float* rot    = (const float*)d_in[2];
    const float* trans  = (const float*)d_in[3];
    const float* mask   = (const float*)d_in[4];
    const float* Wq     = (const float*)d_in[5];
    const float* bq     = (const float*)d_in[6];
    const float* Wkv    = (const float*)d_in[7];
    const float* bkv    = (const float*)d_in[8];
    const float* Wqp    = (const float*)d_in[9];
    const float* bqp    = (const float*)d_in[10];
    const float* Wkvp   = (const float*)d_in[11];
    const float* bkvp   = (const float*)d_in[12];
    const float* Wb     = (const float*)d_in[13];
    const float* bb     = (const float*)d_in[14];
    const float* head_w = (const float*)d_in[15];
    const float* Wout   = (const float*)d_in[16];
    const float* bout   = (const float*)d_in[17];
    float* out = (float*)d_out;
    float* ws  = (float*)d_ws;

    // lifetimes: qpr/kvpr die after krot; q/kT/kpT/qp die after kqk;
    // lqd dies after kfuse (ptmp aliases it); opart/vpart/ssum: kfuse->kepi.
    float* vall  = ws;               // 368640
    float* mpart = ws + 368640;      // 110592
    float* ssum  = ws + 479232;      // 4*12*768 = 36864
    float* cat   = ws + 516096;      // 1622016
    float* lqd   = ws + 2138112;     // 7077888  (reused as ptmp after kfuse)
    float* opart = ws + 9216000;     // 4*768*1536 = 4718592
    float* vpart = ws + 13934592;    // 4*768*480 = 1474560
    float* q     = ws + 15409152;    // 147456
    float* kT    = ws + 15556608;    // 147456
    float* kpT   = ws + 15704064;    // 110592
    float* qp    = ws + 15814656;    // 110592
    float* qpr   = ws + 15925248;    // 110592
    float* kvpr  = ws + 16035840;    // 331776  -> ends 16367616
    float* ptmp  = lqd;              // 1769472 (lqd dead by koutp)

    kproj<<<dim3(96, 9), 256, 0, stream>>>(s, Wq, bq, Wkv, bkv, Wqp, bqp, Wkvp, bkvp,
                                           q, kT, vall, qpr, kvpr);
    krot<<<dim3(768), 192, 0, stream>>>(rot, trans, qpr, kvpr, qp, kpT, vall);
    kqk<<<dim3(12, 24), 256, 0, stream>>>(kT, kpT, q, qp, mask, head_w, bb, lqd, mpart);
    kfuse<<<dim3(768, 4), 256, 0, stream>>>(z, Wb, lqd, mpart, vall, opart, vpart, ssum);
    kepi<<<dim3(768), 256, 0, stream>>>(opart, vpart, ssum, rot, trans, cat);
    koutp<<<dim3(24, 6, 6), 256, 0, stream>>>(cat, Wout, ptmp);
    kred<<<dim3(1152), 256, 0, stream>>>(ptmp, bout, out);
}

// Round 15
// 394.026 us; speedup vs baseline: 1.0436x; 1.0436x over previous
//
#include <hip/hip_runtime.h>
#include <math.h>

#define NN 768
#define CS 384
#define CZ 128
#define CH 16
#define HH 12
#define PQ 4
#define PV 8
#define OUTIN 2112

#define SC_QK 0.14433756729740643f   // sqrt(1/(3*16))
#define SC_B  0.57735026918962576f   // sqrt(1/3)
#define SC_HW 0.13608276348795434f   // sqrt(2/(27*4))
#define MSLACK 12.0f                 // safe-softmax headroom over lqd row max

// DPP cross-lane ops on the VALU pipe. After xor1+xor2, quad-mates are equal,
// so half_mirror(0x141) acts as xor4 and row_mirror(0x140) as xor8.
__device__ __forceinline__ float dpp_add(float x, const int ctrl) {
    int yi;
    switch (ctrl) {
        case 0: yi = __builtin_amdgcn_update_dpp(0, __float_as_int(x), 0xB1,  0xf, 0xf, true); break;
        case 1: yi = __builtin_amdgcn_update_dpp(0, __float_as_int(x), 0x4E,  0xf, 0xf, true); break;
        case 2: yi = __builtin_amdgcn_update_dpp(0, __float_as_int(x), 0x141, 0xf, 0xf, true); break;
        default:yi = __builtin_amdgcn_update_dpp(0, __float_as_int(x), 0x140, 0xf, 0xf, true); break;
    }
    return x + __int_as_float(yi);
}
__device__ __forceinline__ float dpp_max(float x, const int ctrl) {
    int yi;
    switch (ctrl) {
        case 0: yi = __builtin_amdgcn_update_dpp(0, __float_as_int(x), 0xB1,  0xf, 0xf, true); break;
        case 1: yi = __builtin_amdgcn_update_dpp(0, __float_as_int(x), 0x4E,  0xf, 0xf, true); break;
        case 2: yi = __builtin_amdgcn_update_dpp(0, __float_as_int(x), 0x141, 0xf, 0xf, true); break;
        default:yi = __builtin_amdgcn_update_dpp(0, __float_as_int(x), 0x140, 0xf, 0xf, true); break;
    }
    return fmaxf(x, __int_as_float(yi));
}

// ---------------- Kernel A: input projections (s @ W.T + b) ----------------
__global__ __launch_bounds__(256) void kproj(
    const float* __restrict__ s,
    const float* __restrict__ Wq,  const float* __restrict__ bq,
    const float* __restrict__ Wkv, const float* __restrict__ bkv,
    const float* __restrict__ Wqp, const float* __restrict__ bqp,
    const float* __restrict__ Wkvp,const float* __restrict__ bkvp,
    float* __restrict__ q, float* __restrict__ kT, float* __restrict__ vall,
    float* __restrict__ qpr, float* __restrict__ kvpr)
{
    __shared__ float s_lds[8*384];
    int n0 = blockIdx.x * 8;
    int t = threadIdx.x;
    for (int idx = t; idx < 8*384; idx += 256)
        s_lds[idx] = s[(n0 + idx/384)*384 + (idx%384)];
    __syncthreads();

    int o = blockIdx.y * 128 + (t & 127);
    int ng = t >> 7;
    const float* wrow; float bias;
    if (o < 192)      { wrow = Wq   + o*384;       bias = bq[o]; }
    else if (o < 576) { wrow = Wkv  + (o-192)*384; bias = bkv[o-192]; }
    else if (o < 720) { wrow = Wqp  + (o-576)*384; bias = bqp[o-576]; }
    else              { wrow = Wkvp + (o-720)*384; bias = bkvp[o-720]; }

    float acc[4] = {bias, bias, bias, bias};
    const float4* wr4 = reinterpret_cast<const float4*>(wrow);
    for (int c4 = 0; c4 < 96; ++c4) {
        float4 w = wr4[c4];
        #pragma unroll
        for (int nn = 0; nn < 4; ++nn) {
            const float* sr = &s_lds[(ng*4+nn)*384 + c4*4];
            acc[nn] = fmaf(w.x, sr[0], acc[nn]);
            acc[nn] = fmaf(w.y, sr[1], acc[nn]);
            acc[nn] = fmaf(w.z, sr[2], acc[nn]);
            acc[nn] = fmaf(w.w, sr[3], acc[nn]);
        }
    }
    #pragma unroll
    for (int nn = 0; nn < 4; ++nn) {
        int n = n0 + ng*4 + nn;
        float v = acc[nn];
        if (o < 192)      q[n*192 + o] = v;
        else if (o < 576) {
            int oo = o - 192, h = oo >> 5, cc = oo & 31;
            if (cc < 16) kT[(h*NN + n)*16 + cc] = v;
            else         vall[(size_t)n*480 + h*40 + (cc-16)] = v;
        }
        else if (o < 720) qpr[n*144 + (o-576)] = v;
        else              kvpr[n*432 + (o-720)] = v;
    }
}

// ---------------- Kernel B: apply frames (rot, trans) to points ----------------
__global__ __launch_bounds__(192) void krot(
    const float* __restrict__ rot, const float* __restrict__ trans,
    const float* __restrict__ qpr, const float* __restrict__ kvpr,
    float* __restrict__ qp, float* __restrict__ kpT, float* __restrict__ vall)
{
    int n = blockIdx.x;
    __shared__ float R[9], T[3];
    int t = threadIdx.x;
    if (t < 9) R[t] = rot[n*9 + t];
    if (t < 3) T[t] = trans[n*3 + t];
    __syncthreads();

    const float* src = (t < 48) ? (qpr + n*144 + t*3) : (kvpr + n*432 + (t-48)*3);
    float x = src[0], y = src[1], z = src[2];
    float wx = R[0]*x + R[1]*y + R[2]*z + T[0];
    float wy = R[3]*x + R[4]*y + R[5]*z + T[1];
    float wz = R[6]*x + R[7]*y + R[8]*z + T[2];
    if (t < 48) {
        float* d = qp + n*144 + t*3;
        d[0]=wx; d[1]=wy; d[2]=wz;
    } else {
        int pi = t - 48, h = pi/12, pp = pi%12;
        if (pp < 4) {
            float* d = kpT + (h*NN+n)*12 + pp*3;
            d[0]=wx; d[1]=wy; d[2]=wz;
        } else {
            float* d = vall + (size_t)n*480 + h*40 + 16 + (pp-4)*3;
            d[0]=wx; d[1]=wy; d[2]=wz;
        }
    }
}

// ---------------- Kernel C1: z-independent logits + per-tile row max ----------------
__global__ __launch_bounds__(256) void kqk(
    const float* __restrict__ kT, const float* __restrict__ kpT,
    const float* __restrict__ q, const float* __restrict__ qp,
    const float* __restrict__ mask, const float* __restrict__ head_w,
    const float* __restrict__ bb, float* __restrict__ lqd,
    float* __restrict__ mpart)
{
    const int j0 = blockIdx.x * 64;
    const int i0 = blockIdx.y * 32;
    __shared__ float ktl[64][17], kpl[64][13];
    __shared__ float ql[32][17],  qpl[32][13];
    __shared__ float mi_l[32], mj_l[64];
    __shared__ float mpl[32][12];
    const int t = threadIdx.x;
    if (t < 32) mi_l[t] = mask[i0 + t];
    if (t < 64) mj_l[t] = mask[j0 + t];

    const int jl = t & 63, wv = t >> 6;

    for (int h = 0; h < 12; ++h) {
        __syncthreads();
        for (int idx = t; idx < 1024; idx += 256)
            ktl[idx >> 4][idx & 15] = kT[(size_t)(h*NN + j0 + (idx >> 4))*16 + (idx & 15)];
        for (int idx = t; idx < 768; idx += 256) {
            int r = idx / 12, e = idx - r*12;
            kpl[r][e] = kpT[(size_t)(h*NN + j0 + r)*12 + e];
        }
        for (int idx = t; idx < 512; idx += 256)
            ql[idx >> 4][idx & 15] = q[(i0 + (idx >> 4))*192 + h*16 + (idx & 15)];
        for (int idx = t; idx < 384; idx += 256) {
            int r = idx / 12, e = idx - r*12;
            qpl[r][e] = qp[(i0 + r)*144 + h*12 + e];
        }
        __syncthreads();

        const float hwh = log1pf(expf(head_w[h])) * SC_HW;
        const float bbh = bb[h] * SC_B;
        const float mj = mj_l[jl];
        #pragma unroll
        for (int k = 0; k < 8; ++k) {
            const int il = wv*8 + k;
            float qk = 0.f;
            #pragma unroll
            for (int c = 0; c < 16; ++c) qk = fmaf(ktl[jl][c], ql[il][c], qk);
            float d2 = 0.f;
            #pragma unroll
            for (int e = 0; e < 12; ++e) { float d = qpl[il][e] - kpl[jl][e]; d2 = fmaf(d, d, d2); }
            float mt = 1e9f * (mi_l[il]*mj - 1.0f);
            float lg = fmaf(qk, SC_QK, fmaf(-0.5f*hwh, d2, bbh)) + mt;
            lqd[((size_t)(i0+il)*NN + j0 + jl)*12 + h] = lg;
            float m = lg;
            m = dpp_max(m, 0);
            m = dpp_max(m, 1);
            m = dpp_max(m, 2);
            m = dpp_max(m, 3);
            m = fmaxf(m, __shfl_xor(m, 16, 64));
            m = fmaxf(m, __shfl_xor(m, 32, 64));
            if (jl == 0) mpl[il][h] = m;
        }
    }
    __syncthreads();
    if (t < 384) {
        int il = t / 12, h = t - il*12;
        mpart[((size_t)h*NN + i0 + il)*12 + blockIdx.x] = mpl[il][h];
    }
}

// ---------------- Kernel C2: FUSED bias + safe-M exp + register o_pair + o/o_pt ----------------
// grid (768 i, 4 jsegs of 192). z read from HBM exactly ONCE, used in registers
// for BOTH the bias dot and the o_pair accumulate (post-butterfly, every lane
// holds all 6 reduced sums). p only round-trips LDS for the vall matvec.
__global__ __launch_bounds__(256) void kfuse(
    const float* __restrict__ z, const float* __restrict__ Wb,
    const float* __restrict__ lqd, const float* __restrict__ mpart,
    const float* __restrict__ vall,
    float* __restrict__ opart, float* __restrict__ vpart, float* __restrict__ ssum)
{
    __shared__ float  M_lds[12];
    __shared__ __align__(16) float p_lds[12][68];
    __shared__ __align__(16) float oacc[12][128];
    __shared__ float  sredL[16][6];

    const int i = blockIdx.x, jseg = blockIdx.y;
    const int t = threadIdx.x;
    const int gid = t >> 4, cl = t & 15;
    const int hhalf = gid & 1, h0 = hhalf * 6, jofs = gid >> 1;

    if (t < 12) {
        const float4* mp = (const float4*)(mpart + ((size_t)t*NN + i)*12);
        float4 a = mp[0], b = mp[1], c = mp[2];
        float m = fmaxf(fmaxf(fmaxf(a.x,a.y), fmaxf(a.z,a.w)),
                 fmaxf(fmaxf(fmaxf(b.x,b.y), fmaxf(b.z,b.w)),
                       fmaxf(fmaxf(c.x,c.y), fmaxf(c.z,c.w))));
        M_lds[t] = m + MSLACK;
    }

    // Wb fragment: heads h0..h0+5, channels cl*8..cl*8+7  (12 float4 = 48 VGPR)
    float4 wva[6], wvb[6];
    #pragma unroll
    for (int h = 0; h < 6; ++h) {
        const float4* wp = (const float4*)(Wb + (h0+h)*CZ + cl*8);
        wva[h] = wp[0]; wvb[h] = wp[1];
    }

    // o_pair accumulators: 6 heads x 8 channels (this lane's z fragment)
    float4 oaA[6], oaB[6];
    #pragma unroll
    for (int h = 0; h < 6; ++h) {
        oaA[h].x = 0.f; oaA[h].y = 0.f; oaA[h].z = 0.f; oaA[h].w = 0.f;
        oaB[h].x = 0.f; oaB[h].y = 0.f; oaB[h].z = 0.f; oaB[h].w = 0.f;
    }

    float2 vacc; vacc.x = 0.f; vacc.y = 0.f;
    const int vch = 2*t;            // valid for t<240
    const int vh  = (t < 240) ? (vch / 40) : 0;
    float s_acc = 0.f;

    __syncthreads();
    const float M0 = M_lds[h0+0], M1 = M_lds[h0+1], M2 = M_lds[h0+2];
    const float M3 = M_lds[h0+3], M4 = M_lds[h0+4], M5 = M_lds[h0+5];
    const int jbase = jseg * 192;

    for (int tile = 0; tile < 3; ++tile) {
        const int jt = jbase + tile*64;

        // ---- phase 1 (+ in-register o_pair): 8 j per group-iteration ----
        {
            const float4* zq0 = (const float4*)(z + ((size_t)i*NN + jt + jofs)*CZ) + cl*2;
            float4 za = zq0[0], zb = zq0[1];
            for (int it = 0; it < 8; ++it) {
                float4 zaN = za, zbN = zb;
                if (it + 1 < 8) {
                    const float4* zq = (const float4*)(z + ((size_t)i*NN + jt + (it+1)*8 + jofs)*CZ) + cl*2;
                    zaN = zq[0]; zbN = zq[1];
                }
                const int j = jt + it*8 + jofs;
                float b0, b1, b2, b3, b4, b5;
                #define BDOT(BV, H)                                \
                    BV = za.x*wva[H].x;                            \
                    BV = fmaf(za.y, wva[H].y, BV);                 \
                    BV = fmaf(za.z, wva[H].z, BV);                 \
                    BV = fmaf(za.w, wva[H].w, BV);                 \
                    BV = fmaf(zb.x, wvb[H].x, BV);                 \
                    BV = fmaf(zb.y, wvb[H].y, BV);                 \
                    BV = fmaf(zb.z, wvb[H].z, BV);                 \
                    BV = fmaf(zb.w, wvb[H].w, BV);
                BDOT(b0, 0) BDOT(b1, 1) BDOT(b2, 2) BDOT(b3, 3) BDOT(b4, 4) BDOT(b5, 5)
                #undef BDOT
                #define BRED(BV)                                   \
                    BV = dpp_add(BV, 0);                           \
                    BV = dpp_add(BV, 1);                           \
                    BV = dpp_add(BV, 2);                           \
                    BV = dpp_add(BV, 3);
                BRED(b0) BRED(b1) BRED(b2) BRED(b3) BRED(b4) BRED(b5)
                #undef BRED
                // every lane now holds the full 6 bias sums for j
                const float* lq = lqd + ((size_t)i*NN + j)*12 + h0;
                float2 q01 = *(const float2*)(lq + 0);
                float2 q23 = *(const float2*)(lq + 2);
                float2 q45 = *(const float2*)(lq + 4);
                float p0 = __expf(fmaf(b0, SC_B, q01.x) - M0);
                float p1 = __expf(fmaf(b1, SC_B, q01.y) - M1);
                float p2 = __expf(fmaf(b2, SC_B, q23.x) - M2);
                float p3 = __expf(fmaf(b3, SC_B, q23.y) - M3);
                float p4 = __expf(fmaf(b4, SC_B, q45.x) - M4);
                float p5 = __expf(fmaf(b5, SC_B, q45.y) - M5);

                // in-register o_pair accumulate (48 independent FMAs)
                #define OACC(K, PV)                                              \
                    oaA[K].x = fmaf(PV, za.x, oaA[K].x);                         \
                    oaA[K].y = fmaf(PV, za.y, oaA[K].y);                         \
                    oaA[K].z = fmaf(PV, za.z, oaA[K].z);                         \
                    oaA[K].w = fmaf(PV, za.w, oaA[K].w);                         \
                    oaB[K].x = fmaf(PV, zb.x, oaB[K].x);                         \
                    oaB[K].y = fmaf(PV, zb.y, oaB[K].y);                         \
                    oaB[K].z = fmaf(PV, zb.z, oaB[K].z);                         \
                    oaB[K].w = fmaf(PV, zb.w, oaB[K].w);
                OACC(0, p0) OACC(1, p1) OACC(2, p2) OACC(3, p3) OACC(4, p4) OACC(5, p5)
                #undef OACC

                // p_lds (for phase 2b) + denominator, one head per low lane
                float ps = p0;
                ps = (cl == 1) ? p1 : ps;
                ps = (cl == 2) ? p2 : ps;
                ps = (cl == 3) ? p3 : ps;
                ps = (cl == 4) ? p4 : ps;
                ps = (cl == 5) ? p5 : ps;
                if (cl < 6) {
                    p_lds[h0 + cl][j - jt] = ps;
                    s_acc += ps;
                }
                za = zaN; zb = zbN;
            }
        }
        __syncthreads();   // p_lds complete for this tile

        // ---- phase 2b: o/o_pt partial; p via float4 LDS broadcast ----
        if (t < 240) {
            const float2* vr = (const float2*)(vall + (size_t)jt*480 + vch);
            #pragma unroll 4
            for (int q4 = 0; q4 < 16; ++q4) {
                float4 pv = *(const float4*)&p_lds[vh][q4*4];
                float2 v0 = vr[(size_t)(q4*4+0)*240];
                float2 v1 = vr[(size_t)(q4*4+1)*240];
                float2 v2 = vr[(size_t)(q4*4+2)*240];
                float2 v3 = vr[(size_t)(q4*4+3)*240];
                vacc.x = fmaf(pv.x, v0.x, vacc.x); vacc.y = fmaf(pv.x, v0.y, vacc.y);
                vacc.x = fmaf(pv.y, v1.x, vacc.x); vacc.y = fmaf(pv.y, v1.y, vacc.y);
                vacc.x = fmaf(pv.z, v2.x, vacc.x); vacc.y = fmaf(pv.z, v2.y, vacc.y);
                vacc.x = fmaf(pv.w, v3.x, vacc.x); vacc.y = fmaf(pv.w, v3.y, vacc.y);
            }
        }
        __syncthreads();   // p_lds reads done -> next tile may overwrite
    }

    // ---- per-block partial writes ----
    if (cl < 6) sredL[gid][cl] = s_acc;
    if (t < 240)
        *((float2*)(vpart + ((size_t)(jseg*NN + i))*480) + t) = vacc;

    // staged accumulate of register o_pair into oacc[12][128] (8 rounds)
    for (int g = 0; g < 8; ++g) {
        if (jofs == g) {
            #pragma unroll
            for (int k = 0; k < 6; ++k) {
                float4* pa = (float4*)&oacc[h0+k][cl*8];
                float4* pb = (float4*)&oacc[h0+k][cl*8+4];
                if (g == 0) {
                    pa[0] = oaA[k];
                    pb[0] = oaB[k];
                } else {
                    float4 a = pa[0], b = pb[0];
                    a.x += oaA[k].x; a.y += oaA[k].y; a.z += oaA[k].z; a.w += oaA[k].w;
                    b.x += oaB[k].x; b.y += oaB[k].y; b.z += oaB[k].z; b.w += oaB[k].w;
                    pa[0] = a;
                    pb[0] = b;
                }
            }
        }
        __syncthreads();
    }

    // coalesced opart write (flat [12][128] matches kepi's layout)
    {
        float* opw = opart + ((size_t)(jseg*NN + i))*1536;
        const float* of = &oacc[0][0];
        #pragma unroll
        for (int k = 0; k < 6; ++k) opw[k*256 + t] = of[k*256 + t];
    }
    if (t < 12) {
        float sv = 0.f;
        #pragma unroll
        for (int k = 0; k < 8; ++k) sv += sredL[k*2 + (t/6)][t % 6];
        ssum[(size_t)(jseg*12 + t)*NN + i] = sv;
    }
}

// ---------------- Kernel C3: combine 4 partials, normalize, epilogue ----------------
__global__ __launch_bounds__(256) void kepi(
    const float* __restrict__ opart, const float* __restrict__ vpart,
    const float* __restrict__ ssum, const float* __restrict__ rot,
    const float* __restrict__ trans, float* __restrict__ cat)
{
    __shared__ float sinv[12];
    __shared__ float optl[12][24];
    __shared__ float R[9], T[3];
    const int i = blockIdx.x, t = threadIdx.x;
    if (t < 9) R[t] = rot[i*9 + t];
    if (t < 3) T[t] = trans[i*3 + t];
    if (t >= 16 && t < 28) {
        int h = t - 16;
        sinv[h] = 1.0f / (ssum[(size_t)h*NN + i] + ssum[(size_t)(12+h)*NN + i]
                        + ssum[(size_t)(24+h)*NN + i] + ssum[(size_t)(36+h)*NN + i]);
    }
    __syncthreads();

    float* crow = cat + (size_t)i*OUTIN;
    const float2* op0 = (const float2*)(opart + (size_t)i*1536);
    const float2* op1 = (const float2*)(opart + (size_t)(NN + i)*1536);
    const float2* op2 = (const float2*)(opart + (size_t)(2*NN + i)*1536);
    const float2* op3 = (const float2*)(opart + (size_t)(3*NN + i)*1536);
    #pragma unroll
    for (int k = 0; k < 3; ++k) {
        int slot = k*256 + t;
        int h = slot >> 6, c2 = slot & 63;
        float2 a = op0[slot], b = op1[slot], c = op2[slot], d = op3[slot];
        float sc = sinv[h];
        float2 o;
        o.x = (a.x + b.x + c.x + d.x)*sc;
        o.y = (a.y + b.y + c.y + d.y)*sc;
        *(float2*)(crow + 576 + h*128 + c2*2) = o;
    }
    if (t < 240) {
        const int ch = 2*t, h = ch/40, e = ch%40;
        float2 v0 = *(const float2*)(vpart + (size_t)i*480 + ch);
        float2 v1 = *(const float2*)(vpart + (size_t)(NN + i)*480 + ch);
        float2 v2 = *(const float2*)(vpart + (size_t)(2*NN + i)*480 + ch);
        float2 v3 = *(const float2*)(vpart + (size_t)(3*NN + i)*480 + ch);
        float sc = sinv[h];
        float vx = (v0.x + v1.x + v2.x + v3.x)*sc;
        float vy = (v0.y + v1.y + v2.y + v3.y)*sc;
        if (e < 16) { crow[h*16 + e] = vx; crow[h*16 + e + 1] = vy; }
        else        { optl[h][e-16] = vx; optl[h][e-15] = vy; }
    }
    __syncthreads();
    if (t < 96) {
        int h = t >> 3, pp = t & 7;
        float wx = optl[h][pp*3+0] - T[0];
        float wy = optl[h][pp*3+1] - T[1];
        float wz = optl[h][pp*3+2] - T[2];
        crow[192 + 0*96 + h*8 + pp] = R[0]*wx + R[3]*wy + R[6]*wz;
        crow[192 + 1*96 + h*8 + pp] = R[1]*wx + R[4]*wy + R[7]*wz;
        crow[192 + 2*96 + h*8 + pp] = R[2]*wx + R[5]*wy + R[8]*wz;
        crow[480 + h*8 + pp] = sqrtf(fmaf(wx,wx,fmaf(wy,wy,wz*wz)) + 1e-8f);
    }
}

// ---------------- Kernel D1: out partial = cat-tile @ Wout-tile^T (split-K) ----------------
__global__ __launch_bounds__(256) void koutp(
    const float* __restrict__ cat, const float* __restrict__ Wout,
    float* __restrict__ ptmp)
{
    __shared__ float ct[32][36];
    __shared__ float wt[64][36];
    const int n0 = blockIdx.x * 32, o0 = blockIdx.y * 64;
    const int k0 = blockIdx.z * 352;
    const int t = threadIdx.x;
    const int tn = (t >> 4) * 2;
    const int to = t & 15;

    float a00=0,a01=0,a02=0,a03=0, a10=0,a11=0,a12=0,a13=0;

    for (int c = 0; c < 11; ++c) {
        __syncthreads();
        #pragma unroll
        for (int u = 0; u < 4; ++u) {
            int idx = u*256 + t, r = idx >> 5, cc = idx & 31;
            ct[r][cc] = cat[(size_t)(n0 + r)*OUTIN + k0 + c*32 + cc];
        }
        #pragma unroll
        for (int u = 0; u < 8; ++u) {
            int idx = u*256 + t, r = idx >> 5, cc = idx & 31;
            wt[r][cc] = Wout[(size_t)(o0 + r)*OUTIN + k0 + c*32 + cc];
        }
        __syncthreads();
        #pragma unroll
        for (int kk = 0; kk < 32; kk += 4) {
            float4 c0 = *(const float4*)&ct[tn][kk];
            float4 c1 = *(const float4*)&ct[tn+1][kk];
            float4 w0 = *(const float4*)&wt[to][kk];
            float4 w1 = *(const float4*)&wt[to+16][kk];
            float4 w2 = *(const float4*)&wt[to+32][kk];
            float4 w3 = *(const float4*)&wt[to+48][kk];
            a00 = fmaf(c0.x,w0.x,a00); a00 = fmaf(c0.y,w0.y,a00); a00 = fmaf(c0.z,w0.z,a00); a00 = fmaf(c0.w,w0.w,a00);
            a01 = fmaf(c0.x,w1.x,a01); a01 = fmaf(c0.y,w1.y,a01); a01 = fmaf(c0.z,w1.z,a01); a01 = fmaf(c0.w,w1.w,a01);
            a02 = fmaf(c0.x,w2.x,a02); a02 = fmaf(c0.y,w2.y,a02); a02 = fmaf(c0.z,w2.z,a02); a02 = fmaf(c0.w,w2.w,a02);
            a03 = fmaf(c0.x,w3.x,a03); a03 = fmaf(c0.y,w3.y,a03); a03 = fmaf(c0.z,w3.z,a03); a03 = fmaf(c0.w,w3.w,a03);
            a10 = fmaf(c1.x,w0.x,a10); a10 = fmaf(c1.y,w0.y,a10); a10 = fmaf(c1.z,w0.z,a10); a10 = fmaf(c1.w,w0.w,a10);
            a11 = fmaf(c1.x,w1.x,a11); a11 = fmaf(c1.y,w1.y,a11); a11 = fmaf(c1.z,w1.z,a11); a11 = fmaf(c1.w,w1.w,a11);
            a12 = fmaf(c1.x,w2.x,a12); a12 = fmaf(c1.y,w2.y,a12); a12 = fmaf(c1.z,w2.z,a12); a12 = fmaf(c1.w,w2.w,a12);
            a13 = fmaf(c1.x,w3.x,a13); a13 = fmaf(c1.y,w3.y,a13); a13 = fmaf(c1.z,w3.z,a13); a13 = fmaf(c1.w,w3.w,a13);
        }
    }
    float* pb = ptmp + (size_t)blockIdx.z * (NN*384);
    pb[(size_t)(n0+tn+0)*384 + o0+to+ 0] = a00;
    pb[(size_t)(n0+tn+0)*384 + o0+to+16] = a01;
    pb[(size_t)(n0+tn+0)*384 + o0+to+32] = a02;
    pb[(size_t)(n0+tn+0)*384 + o0+to+48] = a03;
    pb[(size_t)(n0+tn+1)*384 + o0+to+ 0] = a10;
    pb[(size_t)(n0+tn+1)*384 + o0+to+16] = a11;
    pb[(size_t)(n0+tn+1)*384 + o0+to+32] = a12;
    pb[(size_t)(n0+tn+1)*384 + o0+to+48] = a13;
}

// ---------------- Kernel D2: reduce split-K partials + bias ----------------
__global__ __launch_bounds__(256) void kred(
    const float* __restrict__ ptmp, const float* __restrict__ bout,
    float* __restrict__ out)
{
    int idx = blockIdx.x * 256 + threadIdx.x;
    int o = idx % 384;
    float v = bout[o];
    #pragma unroll
    for (int s = 0; s < 6; ++s) v += ptmp[(size_t)s*(NN*384) + idx];
    out[idx] = v;
}

extern "C" void kernel_launch(void* const* d_in, const int* in_sizes, int n_in,
                              void* d_out, int out_size, void* d_ws, size_t ws_size,
                              hipStream_t stream) {
    const float* s      = (const float*)d_in[0];
    const float* z      = (const float*)d_in[1];
    const float* rot    = (const float*)d_in[2];
    const float* trans  = (const float*)d_in[3];
    const float* mask   = (const float*)d_in[4];
    const float* Wq     = (const float*)d_in[5];
    const float* bq     = (const float*)d_in[6];
    const float* Wkv    = (const float*)d_in[7];
    const float* bkv    = (const float*)d_in[8];
    const float* Wqp    = (const float*)d_in[9];
    const float* bqp    = (const float*)d_in[10];
    const float* Wkvp   = (const float*)d_in[11];
    const float* bkvp   = (const float*)d_in[12];
    const float* Wb     = (const float*)d_in[13];
    const float* bb     = (const float*)d_in[14];
    const float* head_w = (const float*)d_in[15];
    const float* Wout   = (const float*)d_in[16];
    const float* bout   = (const float*)d_in[17];
    float* out = (float*)d_out;
    float* ws  = (float*)d_ws;

    float* vall  = ws;               // 368640
    float* mpart = ws + 368640;      // 110592
    float* ssum  = ws + 479232;      // 36864
    float* cat   = ws + 516096;      // 1622016
    float* lqd   = ws + 2138112;     // 7077888  (reused as ptmp after kfuse)
    float* opart = ws + 9216000;     // 4718592
    float* vpart = ws + 13934592;    // 1474560
    float* q     = ws + 15409152;    // 147456
    float* kT    = ws + 15556608;    // 147456
    float* kpT   = ws + 15704064;    // 110592
    float* qp    = ws + 15814656;    // 110592
    float* qpr   = ws + 15925248;    // 110592
    float* kvpr  = ws + 16035840;    // 331776
    float* ptmp  = lqd;              // 1769472 (lqd dead by koutp)

    kproj<<<dim3(96, 9), 256, 0, stream>>>(s, Wq, bq, Wkv, bkv, Wqp, bqp, Wkvp, bkvp,
                                           q, kT, vall, qpr, kvpr);
    krot<<<dim3(768), 192, 0, stream>>>(rot, trans, qpr, kvpr, qp, kpT, vall);
    kqk<<<dim3(12, 24), 256, 0, stream>>>(kT, kpT, q, qp, mask, head_w, bb, lqd, mpart);
    kfuse<<<dim3(768, 4), 256, 0, stream>>>(z, Wb, lqd, mpart, vall, opart, vpart, ssum);
    kepi<<<dim3(768), 256, 0, stream>>>(opart, vpart, ssum, rot, trans, cat);
    koutp<<<dim3(24, 6, 6), 256, 0, stream>>>(cat, Wout, ptmp);
    kred<<<dim3(1152), 256, 0, stream>>>(ptmp, bout, out);
}